// Round 14
// baseline (633.791 us; speedup 1.0000x reference)
//
#include <hip/hip_runtime.h>
#include <math.h>

#define HD 128
#define NEG 0.01f
#define GD 64
#define LDST 136   // LDS row stride in ushorts
#define FST 132    // fp32 staging stride (2-way-free scatter)

typedef short bf16x8 __attribute__((ext_vector_type(8)));
typedef float floatx4 __attribute__((ext_vector_type(4)));

__device__ __forceinline__ unsigned short f2bf(float f) {
    unsigned int u = __float_as_uint(f);
    u += 0x7fffu + ((u >> 16) & 1u);   // RNE
    return (unsigned short)(u >> 16);
}
__device__ __forceinline__ float bf2f(unsigned short b) {
    return __uint_as_float(((unsigned int)b) << 16);
}
__device__ __forceinline__ float sigm(float v) { return 1.f / (1.f + __expf(-v)); }

// row-split helper (used by head): A row from LDS, B streamed
__device__ __forceinline__ void mm64(const unsigned short* __restrict__ ap,
                                     const unsigned short* __restrict__ W,
                                     int m16, int quad, floatx4* acc) {
    #pragma unroll
    for (int ks = 0; ks < 4; ks++) {
        const int koff = ks * 32 + quad * 8;
        bf16x8 a = *(const bf16x8*)(ap + koff);
        #pragma unroll
        for (int cg = 0; cg < 8; cg++) {
            bf16x8 b = *(const bf16x8*)(W + (size_t)(cg * 16 + m16) * HD + koff);
            acc[cg] = __builtin_amdgcn_mfma_f32_16x16x32_bf16(a, b, acc[cg], 0, 0, 0);
        }
    }
}

// column-split helpers: wave owns 2 col-groups, B in registers
__device__ __forceinline__ void loadB(const unsigned short* __restrict__ W,
                                      int w, int m16, int quad, bf16x8 bf[2][4]) {
    #pragma unroll
    for (int cgl = 0; cgl < 2; cgl++)
        #pragma unroll
        for (int ks = 0; ks < 4; ks++)
            bf[cgl][ks] = *(const bf16x8*)(W + (size_t)((2 * w + cgl) * 16 + m16) * HD
                                           + ks * 32 + quad * 8);
}
// 32-row tile: 2 row-groups
__device__ __forceinline__ void mmAcc32(const unsigned short* __restrict__ Atile,
                                        int m16, int quad, const bf16x8 bf[2][4],
                                        floatx4 acc[2][2]) {
    #pragma unroll
    for (int rg = 0; rg < 2; rg++)
        #pragma unroll
        for (int ks = 0; ks < 4; ks++) {
            bf16x8 a = *(const bf16x8*)(Atile + (rg * 16 + m16) * LDST + ks * 32 + quad * 8);
            acc[rg][0] = __builtin_amdgcn_mfma_f32_16x16x32_bf16(a, bf[0][ks], acc[rg][0], 0, 0, 0);
            acc[rg][1] = __builtin_amdgcn_mfma_f32_16x16x32_bf16(a, bf[1][ks], acc[rg][1], 0, 0, 0);
        }
}

// ---- plain MFMA GEMM: C = A_bf[M x 128] @ BT_bf[128 x 128]^T; dense C16 epilogue ----
__global__ __launch_bounds__(256) void gemm_mfma(
    const unsigned short* __restrict__ A, const unsigned short* __restrict__ BT,
    float* __restrict__ C32, unsigned short* __restrict__ C16, int M)
{
    __shared__ unsigned short As[128 * LDST];
    __shared__ unsigned short Bs[128 * LDST];
    const int tid = threadIdx.x;
    const int r0 = blockIdx.x * 128;
    {
        int rowi = tid >> 1, half = tid & 1;
        int gr = r0 + rowi; if (gr >= M) gr = M - 1;
        const float4* sa = (const float4*)(A + (size_t)gr * HD + half * 64);
        float4* da = (float4*)(As + rowi * LDST + half * 64);
        const float4* sb = (const float4*)(BT + (size_t)rowi * HD + half * 64);
        float4* db = (float4*)(Bs + rowi * LDST + half * 64);
        #pragma unroll
        for (int i = 0; i < 8; i++) { da[i] = sa[i]; db[i] = sb[i]; }
    }
    __syncthreads();
    const int wave = tid >> 6, lane = tid & 63;
    const int m16 = lane & 15, quad = lane >> 4;
    floatx4 acc[2][8];
    #pragma unroll
    for (int i = 0; i < 2; i++)
        #pragma unroll
        for (int j = 0; j < 8; j++) acc[i][j] = (floatx4){0.f, 0.f, 0.f, 0.f};
    const unsigned short* ar0 = As + (wave * 32 + m16) * LDST;
    const unsigned short* ar1 = As + (wave * 32 + 16 + m16) * LDST;
    #pragma unroll
    for (int ks = 0; ks < 4; ks++) {
        const int koff = ks * 32 + quad * 8;
        bf16x8 a0 = *(const bf16x8*)(ar0 + koff);
        bf16x8 a1 = *(const bf16x8*)(ar1 + koff);
        #pragma unroll
        for (int cg = 0; cg < 8; cg++) {
            bf16x8 b = *(const bf16x8*)(Bs + (cg * 16 + m16) * LDST + koff);
            acc[0][cg] = __builtin_amdgcn_mfma_f32_16x16x32_bf16(a0, b, acc[0][cg], 0, 0, 0);
            acc[1][cg] = __builtin_amdgcn_mfma_f32_16x16x32_bf16(a1, b, acc[1][cg], 0, 0, 0);
        }
    }
    // C32 path (only first gemm): 64 B-dense per 16 lanes — keep direct
    if (C32) {
        #pragma unroll
        for (int rg = 0; rg < 2; rg++)
            #pragma unroll
            for (int cg = 0; cg < 8; cg++)
                #pragma unroll
                for (int i = 0; i < 4; i++) {
                    int r = r0 + wave * 32 + rg * 16 + quad * 4 + i;
                    if (r < M) C32[(size_t)r * HD + cg * 16 + m16] = acc[rg][cg][i];
                }
    }
    __syncthreads();   // all waves done reading As/Bs
    // stage bf16 C into As (dead), then dense sweep
    #pragma unroll
    for (int rg = 0; rg < 2; rg++)
        #pragma unroll
        for (int cg = 0; cg < 8; cg++)
            #pragma unroll
            for (int i = 0; i < 4; i++)
                As[(wave * 32 + rg * 16 + quad * 4 + i) * LDST + cg * 16 + m16] =
                    f2bf(acc[rg][cg][i]);
    __syncthreads();
    #pragma unroll
    for (int it = 0; it < 8; it++) {
        int idx = it * 2048 + tid * 8;       // ushort index into 128x128 tile
        int rowi = idx >> 7, c = idx & 127;
        int gr = r0 + rowi;
        if (gr < M) {
            uint4 v = *(const uint4*)(As + rowi * LDST + c);
            *(uint4*)(C16 + (size_t)gr * HD + c) = v;
        }
    }
}

// ---- GCN gather+finish (16B/lane: 4 edges per wave-load): h fp32, g bf16 ----
__global__ __launch_bounds__(256) void k_gather_gcn(
    const unsigned short* __restrict__ src, const float* __restrict__ xw,
    const int* __restrict__ csr, const int* __restrict__ offs,
    const float* __restrict__ dinv, const float* __restrict__ bias,
    float* __restrict__ h, unsigned short* __restrict__ g16, int N)
{
    int node = blockIdx.x * 4 + (threadIdx.x >> 6);
    if (node >= N) return;
    int lane = threadIdx.x & 63;
    int sub = lane >> 4, cl = lane & 15;
    int s = offs[node], e = offs[node + 1];
    float acc[8] = {0.f, 0.f, 0.f, 0.f, 0.f, 0.f, 0.f, 0.f};
    int j = s;
    for (; j + 8 <= e; j += 8) {
        int ra = csr[j + sub], rb = csr[j + 4 + sub];
        float sa = dinv[ra], sb = dinv[rb];
        bf16x8 va = *(const bf16x8*)(src + (size_t)ra * HD + cl * 8);
        bf16x8 vb = *(const bf16x8*)(src + (size_t)rb * HD + cl * 8);
        #pragma unroll
        for (int q = 0; q < 8; q++)
            acc[q] += bf2f((unsigned short)va[q]) * sa + bf2f((unsigned short)vb[q]) * sb;
    }
    for (; j < e; j += 4) {
        int jj = j + sub;
        if (jj < e) {
            int r = csr[jj];
            float sc = dinv[r];
            bf16x8 v = *(const bf16x8*)(src + (size_t)r * HD + cl * 8);
            #pragma unroll
            for (int q = 0; q < 8; q++)
                acc[q] += bf2f((unsigned short)v[q]) * sc;
        }
    }
    #pragma unroll
    for (int q = 0; q < 8; q++) {
        acc[q] += __shfl_xor(acc[q], 16);
        acc[q] += __shfl_xor(acc[q], 32);
    }
    if (sub == 0) {
        float dn = dinv[node], dv2 = dn * dn;
        size_t base = (size_t)node * HD + cl * 8;
        float4 xv0 = *(const float4*)(xw + base);
        float4 xv1 = *(const float4*)(xw + base + 4);
        float xs[8] = {xv0.x, xv0.y, xv0.z, xv0.w, xv1.x, xv1.y, xv1.z, xv1.w};
        float o[8];
        #pragma unroll
        for (int q = 0; q < 8; q++) {
            float v = acc[q] * dn + xs[q] * dv2 + bias[cl * 8 + q];
            o[q] = v > 0.f ? v : v * NEG;
        }
        *(float4*)(h + base) = (float4){o[0], o[1], o[2], o[3]};
        *(float4*)(h + base + 4) = (float4){o[4], o[5], o[6], o[7]};
        uint4 st;
        st.x = (unsigned int)f2bf(o[0]) | ((unsigned int)f2bf(o[1]) << 16);
        st.y = (unsigned int)f2bf(o[2]) | ((unsigned int)f2bf(o[3]) << 16);
        st.z = (unsigned int)f2bf(o[4]) | ((unsigned int)f2bf(o[5]) << 16);
        st.w = (unsigned int)f2bf(o[6]) | ((unsigned int)f2bf(o[7]) << 16);
        *(uint4*)(g16 + base) = st;
    }
}

// ---- layer gather (16B/lane: 4 edges per wave-load), bf16 in/out ----
__global__ __launch_bounds__(256) void k_gather_m(
    const unsigned short* __restrict__ src, const int* __restrict__ csr,
    const int* __restrict__ offs, unsigned short* __restrict__ out16, int N)
{
    int node = blockIdx.x * 4 + (threadIdx.x >> 6);
    if (node >= N) return;
    int lane = threadIdx.x & 63;
    int sub = lane >> 4, cl = lane & 15;
    int s = offs[node], e = offs[node + 1];
    float acc[8] = {0.f, 0.f, 0.f, 0.f, 0.f, 0.f, 0.f, 0.f};
    int j = s;
    for (; j + 8 <= e; j += 8) {
        int ra = csr[j + sub], rb = csr[j + 4 + sub];
        bf16x8 va = *(const bf16x8*)(src + (size_t)ra * HD + cl * 8);
        bf16x8 vb = *(const bf16x8*)(src + (size_t)rb * HD + cl * 8);
        #pragma unroll
        for (int q = 0; q < 8; q++)
            acc[q] += bf2f((unsigned short)va[q]) + bf2f((unsigned short)vb[q]);
    }
    for (; j < e; j += 4) {
        int jj = j + sub;
        if (jj < e) {
            int r = csr[jj];
            bf16x8 v = *(const bf16x8*)(src + (size_t)r * HD + cl * 8);
            #pragma unroll
            for (int q = 0; q < 8; q++)
                acc[q] += bf2f((unsigned short)v[q]);
        }
    }
    #pragma unroll
    for (int q = 0; q < 8; q++) {
        acc[q] += __shfl_xor(acc[q], 16);
        acc[q] += __shfl_xor(acc[q], 32);
    }
    if (sub == 0) {
        uint4 st;
        st.x = (unsigned int)f2bf(acc[0]) | ((unsigned int)f2bf(acc[1]) << 16);
        st.y = (unsigned int)f2bf(acc[2]) | ((unsigned int)f2bf(acc[3]) << 16);
        st.z = (unsigned int)f2bf(acc[4]) | ((unsigned int)f2bf(acc[5]) << 16);
        st.w = (unsigned int)f2bf(acc[6]) | ((unsigned int)f2bf(acc[7]) << 16);
        *(uint4*)(out16 + (size_t)node * HD + cl * 8) = st;
    }
}

// ---- GRU gates: 32-row blocks, col-split waves, B in regs, dense staging/writeback ----
// bound (256,6): VGPR cap 85 (kernel uses ~48, no spills); 6 blocks/CU matches grid 6.1/CU
__global__ __launch_bounds__(256, 6) void k_gru_gates(
    const unsigned short* __restrict__ m_bf, const unsigned short* __restrict__ g_bf,
    const unsigned short* __restrict__ Wih, const unsigned short* __restrict__ Whh,
    const float* __restrict__ b_ih, const float* __restrict__ b_hh,
    unsigned short* __restrict__ g16_out, int M)
{
    __shared__ unsigned short sh[2 * 32 * LDST];   // 17408 B; reused as fp32 stage
    unsigned short* Am = sh;
    unsigned short* Ag = sh + 32 * LDST;
    const int tid = threadIdx.x;
    const int r0 = blockIdx.x * 32;
    // dense flat staging: per instruction 256 threads x 16 B contiguous
    #pragma unroll
    for (int it = 0; it < 2; it++) {
        int idx = it * 2048 + tid * 8;   // ushort index in 32x128 tile
        int rowi = idx >> 7, c = idx & 127;
        int gr = r0 + rowi; if (gr >= M) gr = M - 1;
        *(float4*)(Am + rowi * LDST + c) = *(const float4*)(m_bf + (size_t)gr * HD + c);
        *(float4*)(Ag + rowi * LDST + c) = *(const float4*)(g_bf + (size_t)gr * HD + c);
    }
    __syncthreads();
    const int w = tid >> 6, l = tid & 63;
    const int m16 = l & 15, quad = l >> 4;

    floatx4 accA[2][2], accB[2][2];
    bf16x8 bf[2][4];
    #pragma unroll
    for (int rg = 0; rg < 2; rg++)
        #pragma unroll
        for (int c = 0; c < 2; c++) {
            accA[rg][c] = (floatx4){0.f, 0.f, 0.f, 0.f};
            accB[rg][c] = (floatx4){0.f, 0.f, 0.f, 0.f};
        }
    // r-gate: accA = m@Wih_r + g@Whh_r
    loadB(Wih, w, m16, quad, bf);
    mmAcc32(Am, m16, quad, bf, accA);
    loadB(Whh, w, m16, quad, bf);
    mmAcc32(Ag, m16, quad, bf, accA);
    // hn: accB = g@Whh_n
    loadB(Whh + 256 * HD, w, m16, quad, bf);
    mmAcc32(Ag, m16, quad, bf, accB);
    // fold: accB = sigm(r)*(hn + b_hhn)
    #pragma unroll
    for (int cgl = 0; cgl < 2; cgl++) {
        int c = (2 * w + cgl) * 16 + m16;
        float br = b_ih[c] + b_hh[c];
        float bhn = b_hh[256 + c];
        #pragma unroll
        for (int rg = 0; rg < 2; rg++)
            #pragma unroll
            for (int i = 0; i < 4; i++) {
                float r = sigm(accA[rg][cgl][i] + br);
                accB[rg][cgl][i] = r * (accB[rg][cgl][i] + bhn);
            }
    }
    // accB += m@Wih_n
    loadB(Wih + 256 * HD, w, m16, quad, bf);
    mmAcc32(Am, m16, quad, bf, accB);
    // z: accA = m@Wih_z + g@Whh_z
    #pragma unroll
    for (int rg = 0; rg < 2; rg++)
        #pragma unroll
        for (int c = 0; c < 2; c++) accA[rg][c] = (floatx4){0.f, 0.f, 0.f, 0.f};
    loadB(Wih + 128 * HD, w, m16, quad, bf);
    mmAcc32(Am, m16, quad, bf, accA);
    loadB(Whh + 128 * HD, w, m16, quad, bf);
    mmAcc32(Ag, m16, quad, bf, accA);
    // GRU update; old state from the bf16 Ag tile (no global traffic)
    float ov[2][2][4];
    #pragma unroll
    for (int cgl = 0; cgl < 2; cgl++) {
        int c = (2 * w + cgl) * 16 + m16;
        float bz = b_ih[128 + c] + b_hh[128 + c];
        float bin = b_ih[256 + c];
        #pragma unroll
        for (int rg = 0; rg < 2; rg++)
            #pragma unroll
            for (int i = 0; i < 4; i++) {
                float z = sigm(accA[rg][cgl][i] + bz);
                float n = tanhf(accB[rg][cgl][i] + bin);
                float gv = bf2f(Ag[(rg * 16 + quad * 4 + i) * LDST + c]);
                ov[cgl][rg][i] = (1.f - z) * n + z * gv;
            }
    }
    __syncthreads();   // Am/Ag dead; reuse as 32 x FST fp32 staging
    float* shf = (float*)sh;
    #pragma unroll
    for (int cgl = 0; cgl < 2; cgl++) {
        int c = (2 * w + cgl) * 16 + m16;
        #pragma unroll
        for (int rg = 0; rg < 2; rg++)
            #pragma unroll
            for (int i = 0; i < 4; i++)
                shf[(rg * 16 + quad * 4 + i) * FST + c] = ov[cgl][rg][i];
    }
    __syncthreads();
    // dense packed writeback: per instruction 256 threads x 16 B contiguous
    #pragma unroll
    for (int it = 0; it < 2; it++) {
        int idx = it * 2048 + tid * 8;
        int rowi = idx >> 7, c = idx & 127;
        int gr = r0 + rowi;
        if (gr < M) {
            float4 v0 = *(const float4*)(shf + rowi * FST + c);
            float4 v1 = *(const float4*)(shf + rowi * FST + c + 4);
            uint4 st;
            st.x = (unsigned int)f2bf(v0.x) | ((unsigned int)f2bf(v0.y) << 16);
            st.y = (unsigned int)f2bf(v0.z) | ((unsigned int)f2bf(v0.w) << 16);
            st.z = (unsigned int)f2bf(v1.x) | ((unsigned int)f2bf(v1.y) << 16);
            st.w = (unsigned int)f2bf(v1.z) | ((unsigned int)f2bf(v1.w) << 16);
            *(uint4*)(g16_out + (size_t)gr * HD + c) = st;
        }
    }
}

// ---- fused head: h2=leaky(g_bf)+h ; h3=leaky(h2@W1+b1) ; probs=sigm(h3.W2+b2) ----
__global__ __launch_bounds__(256, 4) void k_head_fused(
    const unsigned short* __restrict__ g_bf, const float* __restrict__ h,
    const unsigned short* __restrict__ W1T, const float* __restrict__ b1,
    const float* __restrict__ W2, const float* __restrict__ b2,
    float* __restrict__ probs, int M)
{
    __shared__ unsigned short As[64 * LDST];
    const int tid = threadIdx.x;
    const int r0 = blockIdx.x * 64;
    {
        int rowi = tid >> 2, q = tid & 3;
        int gr = r0 + rowi; if (gr >= M) gr = M - 1;
        const unsigned short* gp = g_bf + (size_t)gr * HD + q * 32;
        const float* hp = h + (size_t)gr * HD + q * 32;
        unsigned short* dst = As + rowi * LDST + q * 32;
        #pragma unroll
        for (int i = 0; i < 32; i += 4) {
            ushort4 gu = *(const ushort4*)(gp + i);
            float4 hv = *(const float4*)(hp + i);
            ushort4 o;
            float v;
            v = bf2f(gu.x); v = v > 0.f ? v : v * NEG; o.x = f2bf(v + hv.x);
            v = bf2f(gu.y); v = v > 0.f ? v : v * NEG; o.y = f2bf(v + hv.y);
            v = bf2f(gu.z); v = v > 0.f ? v : v * NEG; o.z = f2bf(v + hv.z);
            v = bf2f(gu.w); v = v > 0.f ? v : v * NEG; o.w = f2bf(v + hv.w);
            *(ushort4*)(dst + i) = o;
        }
    }
    __syncthreads();
    const int w = tid >> 6, l = tid & 63;
    const int m16 = l & 15, quad = l >> 4;
    floatx4 acc[8];
    #pragma unroll
    for (int j = 0; j < 8; j++) acc[j] = (floatx4){0.f, 0.f, 0.f, 0.f};
    mm64(As + (w * 16 + m16) * LDST, W1T, m16, quad, acc);
    #pragma unroll
    for (int i = 0; i < 4; i++) {
        float s = 0.f;
        #pragma unroll
        for (int cg = 0; cg < 8; cg++) {
            int c = cg * 16 + m16;
            float v = acc[cg][i] + b1[c];
            v = v > 0.f ? v : v * NEG;
            s += v * W2[c];
        }
        s += __shfl_xor(s, 1); s += __shfl_xor(s, 2);
        s += __shfl_xor(s, 4); s += __shfl_xor(s, 8);
        int r = r0 + w * 16 + quad * 4 + i;
        if (m16 == 0 && r < M) probs[r] = sigm(s + b2[0]);
    }
}

// ---- weight prep ----
__global__ void k_prep_w(const float* __restrict__ W_gcn, const float* __restrict__ W_gg,
                         const float* __restrict__ W_ih, const float* __restrict__ W_hh,
                         const float* __restrict__ W1, unsigned short* __restrict__ Wq) {
    int i = blockIdx.x * blockDim.x + threadIdx.x;
    if (i >= 180224) return;
    float v;
    if (i < 16384) {
        int n = i >> 7, k = i & 127;
        v = W_gcn[k * 128 + n];
    } else if (i < 65536) {
        int j = i - 16384;
        int l = j >> 14, rr = j & 16383;
        int n = rr >> 7, k = rr & 127;
        v = W_gg[l * 16384 + k * 128 + n];
    } else if (i < 114688) {
        v = W_ih[i - 65536];
    } else if (i < 163840) {
        v = W_hh[i - 114688];
    } else {
        int j = i - 163840;
        int n = j >> 7, k = j & 127;
        v = W1[k * 128 + n];
    }
    Wq[i] = f2bf(v);
}

__global__ void k_cast_x(const float* __restrict__ s, unsigned short* __restrict__ d, int n2) {
    int i = blockIdx.x * blockDim.x + threadIdx.x;
    if (i >= n2) return;
    float2 v = *(const float2*)(s + (size_t)i * 2);
    unsigned int p = (unsigned int)f2bf(v.x) | ((unsigned int)f2bf(v.y) << 16);
    *(unsigned int*)(d + (size_t)i * 2) = p;
}

// ---- CSR build (4-way sharded histogram) ----
__global__ void k_hist(const int* __restrict__ col, int* __restrict__ cnt4,
                       int* __restrict__ rank, int N, int E) {
    int e = blockIdx.x * blockDim.x + threadIdx.x;
    if (e < E) {
        int s = blockIdx.x & 3;
        rank[e] = atomicAdd(&cnt4[s * N + col[e]], 1);
    }
}

#define SCHUNK 2048
__global__ __launch_bounds__(256) void k_scan1(const int* __restrict__ cnt4,
                                               int* __restrict__ excl,
                                               int* __restrict__ bsum, int N) {
    __shared__ int ts[256];
    int t = threadIdx.x;
    int base = blockIdx.x * SCHUNK + t * 8;
    int v[8]; int s = 0;
    #pragma unroll
    for (int q = 0; q < 8; q++) {
        int i = base + q;
        v[q] = (i < N) ? (cnt4[i] + cnt4[N + i] + cnt4[2 * N + i] + cnt4[3 * N + i]) : 0;
        s += v[q];
    }
    ts[t] = s;
    __syncthreads();
    for (int off = 1; off < 256; off <<= 1) {
        int a = (t >= off) ? ts[t - off] : 0;
        __syncthreads();
        ts[t] += a;
        __syncthreads();
    }
    int run = ts[t] - s;
    #pragma unroll
    for (int q = 0; q < 8; q++) { int i = base + q; if (i < N) excl[i] = run; run += v[q]; }
    if (t == 255) bsum[blockIdx.x] = ts[255];
}

__global__ void k_scan2(int* bsum, int nb) {
    if (threadIdx.x == 0) {
        int run = 0;
        for (int b = 0; b < nb; b++) { int v = bsum[b]; bsum[b] = run; run += v; }
    }
}

__global__ void k_csrfin(const int* __restrict__ excl, const int* __restrict__ bsum,
                         const int* __restrict__ cnt4, int* __restrict__ offs,
                         int* __restrict__ sbase, float* __restrict__ dinv, int N, int E) {
    int i = blockIdx.x * blockDim.x + threadIdx.x;
    if (i >= N) return;
    int o = excl[i] + bsum[i >> 11];
    offs[i] = o;
    if (i == 0) offs[N] = E;
    int c0 = cnt4[i], c1 = cnt4[N + i], c2 = cnt4[2 * N + i], c3 = cnt4[3 * N + i];
    sbase[i] = o;
    sbase[N + i] = o + c0;
    sbase[2 * N + i] = o + c0 + c1;
    sbase[3 * N + i] = o + c0 + c1 + c2;
    dinv[i] = rsqrtf((float)(c0 + c1 + c2 + c3) + 1.f);
}

__global__ void k_fill(const int* __restrict__ row, const int* __restrict__ col,
                       const int* __restrict__ sbase, const int* __restrict__ rank,
                       int* __restrict__ csr_rows, int N, int E) {
    int e = blockIdx.x * blockDim.x + threadIdx.x;
    if (e >= E) return;
    int s = (e >> 8) & 3;   // matches k_hist's blockIdx&3 (blockDim=256)
    csr_rows[sbase[s * N + col[e]] + rank[e]] = row[e];
}

// ---- maxcut loss over edges ----
__global__ __launch_bounds__(256) void k_loss_edge(const float* __restrict__ probs,
                                                   const int* __restrict__ row,
                                                   const int* __restrict__ col,
                                                   const int* __restrict__ batch,
                                                   float* __restrict__ ed,
                                                   float* __restrict__ ew, int E) {
    __shared__ float bd[GD], be[GD];
    if (threadIdx.x < GD) { bd[threadIdx.x] = 0.f; be[threadIdx.x] = 0.f; }
    __syncthreads();
    for (int e = blockIdx.x * blockDim.x + threadIdx.x; e < E; e += gridDim.x * blockDim.x) {
        int r = row[e];
        float pr = probs[r];
        int b = batch[r];
        atomicAdd(&bd[b], pr);
        atomicAdd(&be[b], pr * probs[col[e]]);
    }
    __syncthreads();
    if (threadIdx.x < GD) {
        atomicAdd(&ed[threadIdx.x], bd[threadIdx.x]);
        atomicAdd(&ew[threadIdx.x], be[threadIdx.x]);
    }
}

__global__ void k_finalize(const float* __restrict__ ed, const float* __restrict__ ew,
                           float* __restrict__ out) {
    int g = threadIdx.x;
    if (g < GD) out[g] = -(ed[g] - ew[g]) * 0.5f;
}

extern "C" void kernel_launch(void* const* d_in, const int* in_sizes, int n_in,
                              void* d_out, int out_size, void* d_ws, size_t ws_size,
                              hipStream_t stream) {
    const float* x     = (const float*)d_in[0];
    const int*   ei    = (const int*)d_in[1];
    const int*   batch = (const int*)d_in[2];
    const float* W_gcn = (const float*)d_in[3];
    const float* b_gcn = (const float*)d_in[4];
    const float* W_gg  = (const float*)d_in[5];
    const float* W_ih  = (const float*)d_in[6];
    const float* W_hh  = (const float*)d_in[7];
    const float* b_ih  = (const float*)d_in[8];
    const float* b_hh  = (const float*)d_in[9];
    const float* W1    = (const float*)d_in[10];
    const float* b1    = (const float*)d_in[11];
    const float* W2    = (const float*)d_in[12];
    const float* b2    = (const float*)d_in[13];
    float* out = (float*)d_out;

    const int N = in_sizes[2];
    const int E = in_sizes[1] / 2;
    const int* row = ei;
    const int* col = ei + E;
    const size_t NH = (size_t)N * HD;

    float* F = (float*)d_ws;
    float* f_h  = F + 0 * NH;
    float* f_xw = F + 1 * NH;
    unsigned short* U = (unsigned short*)(F + 2 * NH);
    unsigned short* x_bf  = U;
    unsigned short* g_bf  = U + 1 * NH;
    unsigned short* t_bf  = U + 2 * NH;
    unsigned short* m_bf  = U + 3 * NH;
    unsigned short* Wq    = U + 4 * NH;
    unsigned short* WgcnT = Wq;               // 16384
    unsigned short* WggT  = Wq + 16384;       // 3*16384
    unsigned short* Wih16 = Wq + 65536;       // 49152
    unsigned short* Whh16 = Wq + 114688;      // 49152
    unsigned short* W1T   = Wq + 163840;      // 16384
    float* S = (float*)(Wq + 180224);
    float* f_dinv  = S;
    float* f_probs = S + N;
    float* f_ed    = S + 2 * N;
    float* f_ew    = f_ed + GD;
    int* I = (int*)(f_ew + GD);
    int* i_cnt4  = I;                  // 4N (zeroed)
    int* i_excl  = I + 4 * N;          // N
    int* i_offs  = I + 5 * N;          // N+1
    int* i_bsum  = I + 6 * N + 8;      // <=64
    int* i_sbase = I + 6 * N + 128;    // 4N
    int* i_rank  = I + 10 * N + 128;   // E
    int* i_csr   = i_rank + E;         // E

    const int nb_scan = (N + SCHUNK - 1) / SCHUNK;
    const int gb32 = (N + 31) / 32;
    const int gb64 = (N + 63) / 64;
    const int gb128 = (N + 127) / 128;
    const int eg = (E + 255) / 256;
    const int ng = (N + 255) / 256;
    const int gather_grid = (N + 3) / 4;

    hipMemsetAsync(i_cnt4, 0, sizeof(int) * 4 * (size_t)N, stream);
    hipMemsetAsync(f_ed, 0, sizeof(float) * 2 * GD, stream);

    // weight prep
    k_prep_w<<<704, 256, 0, stream>>>(W_gcn, W_gg, W_ih, W_hh, W1, Wq);
    k_cast_x<<<(int)((NH / 2 + 255) / 256), 256, 0, stream>>>(x, x_bf, (int)(NH / 2));

    // CSR build
    k_hist<<<eg, 256, 0, stream>>>(col, i_cnt4, i_rank, N, E);
    k_scan1<<<nb_scan, 256, 0, stream>>>(i_cnt4, i_excl, i_bsum, N);
    k_scan2<<<1, 64, 0, stream>>>(i_bsum, nb_scan);
    k_csrfin<<<ng, 256, 0, stream>>>(i_excl, i_bsum, i_cnt4, i_offs, i_sbase, f_dinv, N, E);
    k_fill<<<eg, 256, 0, stream>>>(row, col, i_sbase, i_rank, i_csr, N, E);

    // GCN: xw = x@W_gcn (fp32+bf16); gather+finish -> h fp32, g bf16
    gemm_mfma<<<gb128, 256, 0, stream>>>(x_bf, WgcnT, f_xw, t_bf, N);
    k_gather_gcn<<<gather_grid, 256, 0, stream>>>(t_bf, f_xw, i_csr, i_offs, f_dinv,
                                                  b_gcn, f_h, g_bf, N);

    // GatedGraphConv layers: project -> parallel gather -> 32-row gates+GRU (bf16 state)
    for (int l = 0; l < 3; l++) {
        gemm_mfma<<<gb128, 256, 0, stream>>>(g_bf, WggT + (size_t)l * 16384,
                                             nullptr, t_bf, N);
        k_gather_m<<<gather_grid, 256, 0, stream>>>(t_bf, i_csr, i_offs, m_bf, N);
        k_gru_gates<<<gb32, 256, 0, stream>>>(m_bf, g_bf, Wih16, Whh16, b_ih, b_hh,
                                              g_bf, N);
    }

    // fused head (reads bf16 g state + fp32 h)
    k_head_fused<<<gb64, 256, 0, stream>>>(g_bf, f_h, W1T, b1, W2, b2, f_probs, N);

    // maxcut loss (expected_degree folded into edge pass — exact identity)
    k_loss_edge<<<1024, 256, 0, stream>>>(f_probs, row, col, batch, f_ed, f_ew, E);
    k_finalize<<<1, 64, 0, stream>>>(f_ed, f_ew, out);
}

// Round 15
// 586.639 us; speedup vs baseline: 1.0804x; 1.0804x over previous
//
#include <hip/hip_runtime.h>
#include <math.h>

#define HD 128
#define NEG 0.01f
#define GD 64
#define LDST 136   // LDS row stride in ushorts
#define FST 132    // fp32 staging stride (2-way-free scatter)

typedef short bf16x8 __attribute__((ext_vector_type(8)));
typedef float floatx4 __attribute__((ext_vector_type(4)));

__device__ __forceinline__ unsigned short f2bf(float f) {
    unsigned int u = __float_as_uint(f);
    u += 0x7fffu + ((u >> 16) & 1u);   // RNE
    return (unsigned short)(u >> 16);
}
__device__ __forceinline__ float bf2f(unsigned short b) {
    return __uint_as_float(((unsigned int)b) << 16);
}
__device__ __forceinline__ float sigm(float v) { return 1.f / (1.f + __expf(-v)); }

// row-split helper (used by head): A row from LDS, B streamed
__device__ __forceinline__ void mm64(const unsigned short* __restrict__ ap,
                                     const unsigned short* __restrict__ W,
                                     int m16, int quad, floatx4* acc) {
    #pragma unroll
    for (int ks = 0; ks < 4; ks++) {
        const int koff = ks * 32 + quad * 8;
        bf16x8 a = *(const bf16x8*)(ap + koff);
        #pragma unroll
        for (int cg = 0; cg < 8; cg++) {
            bf16x8 b = *(const bf16x8*)(W + (size_t)(cg * 16 + m16) * HD + koff);
            acc[cg] = __builtin_amdgcn_mfma_f32_16x16x32_bf16(a, b, acc[cg], 0, 0, 0);
        }
    }
}

// column-split helpers: wave owns 2 col-groups, B in registers
__device__ __forceinline__ void loadB(const unsigned short* __restrict__ W,
                                      int w, int m16, int quad, bf16x8 bf[2][4]) {
    #pragma unroll
    for (int cgl = 0; cgl < 2; cgl++)
        #pragma unroll
        for (int ks = 0; ks < 4; ks++)
            bf[cgl][ks] = *(const bf16x8*)(W + (size_t)((2 * w + cgl) * 16 + m16) * HD
                                           + ks * 32 + quad * 8);
}
// 32-row tile: 2 row-groups
__device__ __forceinline__ void mmAcc32(const unsigned short* __restrict__ Atile,
                                        int m16, int quad, const bf16x8 bf[2][4],
                                        floatx4 acc[2][2]) {
    #pragma unroll
    for (int rg = 0; rg < 2; rg++)
        #pragma unroll
        for (int ks = 0; ks < 4; ks++) {
            bf16x8 a = *(const bf16x8*)(Atile + (rg * 16 + m16) * LDST + ks * 32 + quad * 8);
            acc[rg][0] = __builtin_amdgcn_mfma_f32_16x16x32_bf16(a, bf[0][ks], acc[rg][0], 0, 0, 0);
            acc[rg][1] = __builtin_amdgcn_mfma_f32_16x16x32_bf16(a, bf[1][ks], acc[rg][1], 0, 0, 0);
        }
}

// ---- plain MFMA GEMM: C = A_bf[M x 128] @ BT_bf[128 x 128]^T; dense C16 epilogue ----
__global__ __launch_bounds__(256) void gemm_mfma(
    const unsigned short* __restrict__ A, const unsigned short* __restrict__ BT,
    float* __restrict__ C32, unsigned short* __restrict__ C16, int M)
{
    __shared__ unsigned short As[128 * LDST];
    __shared__ unsigned short Bs[128 * LDST];
    const int tid = threadIdx.x;
    const int r0 = blockIdx.x * 128;
    {
        int rowi = tid >> 1, half = tid & 1;
        int gr = r0 + rowi; if (gr >= M) gr = M - 1;
        const float4* sa = (const float4*)(A + (size_t)gr * HD + half * 64);
        float4* da = (float4*)(As + rowi * LDST + half * 64);
        const float4* sb = (const float4*)(BT + (size_t)rowi * HD + half * 64);
        float4* db = (float4*)(Bs + rowi * LDST + half * 64);
        #pragma unroll
        for (int i = 0; i < 8; i++) { da[i] = sa[i]; db[i] = sb[i]; }
    }
    __syncthreads();
    const int wave = tid >> 6, lane = tid & 63;
    const int m16 = lane & 15, quad = lane >> 4;
    floatx4 acc[2][8];
    #pragma unroll
    for (int i = 0; i < 2; i++)
        #pragma unroll
        for (int j = 0; j < 8; j++) acc[i][j] = (floatx4){0.f, 0.f, 0.f, 0.f};
    const unsigned short* ar0 = As + (wave * 32 + m16) * LDST;
    const unsigned short* ar1 = As + (wave * 32 + 16 + m16) * LDST;
    #pragma unroll
    for (int ks = 0; ks < 4; ks++) {
        const int koff = ks * 32 + quad * 8;
        bf16x8 a0 = *(const bf16x8*)(ar0 + koff);
        bf16x8 a1 = *(const bf16x8*)(ar1 + koff);
        #pragma unroll
        for (int cg = 0; cg < 8; cg++) {
            bf16x8 b = *(const bf16x8*)(Bs + (cg * 16 + m16) * LDST + koff);
            acc[0][cg] = __builtin_amdgcn_mfma_f32_16x16x32_bf16(a0, b, acc[0][cg], 0, 0, 0);
            acc[1][cg] = __builtin_amdgcn_mfma_f32_16x16x32_bf16(a1, b, acc[1][cg], 0, 0, 0);
        }
    }
    // C32 path (only first gemm): 64 B-dense per 16 lanes — keep direct
    if (C32) {
        #pragma unroll
        for (int rg = 0; rg < 2; rg++)
            #pragma unroll
            for (int cg = 0; cg < 8; cg++)
                #pragma unroll
                for (int i = 0; i < 4; i++) {
                    int r = r0 + wave * 32 + rg * 16 + quad * 4 + i;
                    if (r < M) C32[(size_t)r * HD + cg * 16 + m16] = acc[rg][cg][i];
                }
    }
    __syncthreads();   // all waves done reading As/Bs
    // stage bf16 C into As (dead), then dense sweep
    #pragma unroll
    for (int rg = 0; rg < 2; rg++)
        #pragma unroll
        for (int cg = 0; cg < 8; cg++)
            #pragma unroll
            for (int i = 0; i < 4; i++)
                As[(wave * 32 + rg * 16 + quad * 4 + i) * LDST + cg * 16 + m16] =
                    f2bf(acc[rg][cg][i]);
    __syncthreads();
    #pragma unroll
    for (int it = 0; it < 8; it++) {
        int idx = it * 2048 + tid * 8;       // ushort index into 128x128 tile
        int rowi = idx >> 7, c = idx & 127;
        int gr = r0 + rowi;
        if (gr < M) {
            uint4 v = *(const uint4*)(As + rowi * LDST + c);
            *(uint4*)(C16 + (size_t)gr * HD + c) = v;
        }
    }
}

// ---- GCN gather+finish (16B/lane: 4 edges per wave-load): h fp32, g bf16 ----
__global__ __launch_bounds__(256) void k_gather_gcn(
    const unsigned short* __restrict__ src, const float* __restrict__ xw,
    const int* __restrict__ csr, const int* __restrict__ offs,
    const float* __restrict__ dinv, const float* __restrict__ bias,
    float* __restrict__ h, unsigned short* __restrict__ g16, int N)
{
    int node = blockIdx.x * 4 + (threadIdx.x >> 6);
    if (node >= N) return;
    int lane = threadIdx.x & 63;
    int sub = lane >> 4, cl = lane & 15;
    int s = offs[node], e = offs[node + 1];
    float acc[8] = {0.f, 0.f, 0.f, 0.f, 0.f, 0.f, 0.f, 0.f};
    int j = s;
    for (; j + 8 <= e; j += 8) {
        int ra = csr[j + sub], rb = csr[j + 4 + sub];
        float sa = dinv[ra], sb = dinv[rb];
        bf16x8 va = *(const bf16x8*)(src + (size_t)ra * HD + cl * 8);
        bf16x8 vb = *(const bf16x8*)(src + (size_t)rb * HD + cl * 8);
        #pragma unroll
        for (int q = 0; q < 8; q++)
            acc[q] += bf2f((unsigned short)va[q]) * sa + bf2f((unsigned short)vb[q]) * sb;
    }
    for (; j < e; j += 4) {
        int jj = j + sub;
        if (jj < e) {
            int r = csr[jj];
            float sc = dinv[r];
            bf16x8 v = *(const bf16x8*)(src + (size_t)r * HD + cl * 8);
            #pragma unroll
            for (int q = 0; q < 8; q++)
                acc[q] += bf2f((unsigned short)v[q]) * sc;
        }
    }
    #pragma unroll
    for (int q = 0; q < 8; q++) {
        acc[q] += __shfl_xor(acc[q], 16);
        acc[q] += __shfl_xor(acc[q], 32);
    }
    if (sub == 0) {
        float dn = dinv[node], dv2 = dn * dn;
        size_t base = (size_t)node * HD + cl * 8;
        float4 xv0 = *(const float4*)(xw + base);
        float4 xv1 = *(const float4*)(xw + base + 4);
        float xs[8] = {xv0.x, xv0.y, xv0.z, xv0.w, xv1.x, xv1.y, xv1.z, xv1.w};
        float o[8];
        #pragma unroll
        for (int q = 0; q < 8; q++) {
            float v = acc[q] * dn + xs[q] * dv2 + bias[cl * 8 + q];
            o[q] = v > 0.f ? v : v * NEG;
        }
        *(float4*)(h + base) = (float4){o[0], o[1], o[2], o[3]};
        *(float4*)(h + base + 4) = (float4){o[4], o[5], o[6], o[7]};
        uint4 st;
        st.x = (unsigned int)f2bf(o[0]) | ((unsigned int)f2bf(o[1]) << 16);
        st.y = (unsigned int)f2bf(o[2]) | ((unsigned int)f2bf(o[3]) << 16);
        st.z = (unsigned int)f2bf(o[4]) | ((unsigned int)f2bf(o[5]) << 16);
        st.w = (unsigned int)f2bf(o[6]) | ((unsigned int)f2bf(o[7]) << 16);
        *(uint4*)(g16 + base) = st;
    }
}

// ---- layer gather (16B/lane: 4 edges per wave-load), bf16 in/out ----
__global__ __launch_bounds__(256) void k_gather_m(
    const unsigned short* __restrict__ src, const int* __restrict__ csr,
    const int* __restrict__ offs, unsigned short* __restrict__ out16, int N)
{
    int node = blockIdx.x * 4 + (threadIdx.x >> 6);
    if (node >= N) return;
    int lane = threadIdx.x & 63;
    int sub = lane >> 4, cl = lane & 15;
    int s = offs[node], e = offs[node + 1];
    float acc[8] = {0.f, 0.f, 0.f, 0.f, 0.f, 0.f, 0.f, 0.f};
    int j = s;
    for (; j + 8 <= e; j += 8) {
        int ra = csr[j + sub], rb = csr[j + 4 + sub];
        bf16x8 va = *(const bf16x8*)(src + (size_t)ra * HD + cl * 8);
        bf16x8 vb = *(const bf16x8*)(src + (size_t)rb * HD + cl * 8);
        #pragma unroll
        for (int q = 0; q < 8; q++)
            acc[q] += bf2f((unsigned short)va[q]) + bf2f((unsigned short)vb[q]);
    }
    for (; j < e; j += 4) {
        int jj = j + sub;
        if (jj < e) {
            int r = csr[jj];
            bf16x8 v = *(const bf16x8*)(src + (size_t)r * HD + cl * 8);
            #pragma unroll
            for (int q = 0; q < 8; q++)
                acc[q] += bf2f((unsigned short)v[q]);
        }
    }
    #pragma unroll
    for (int q = 0; q < 8; q++) {
        acc[q] += __shfl_xor(acc[q], 16);
        acc[q] += __shfl_xor(acc[q], 32);
    }
    if (sub == 0) {
        uint4 st;
        st.x = (unsigned int)f2bf(acc[0]) | ((unsigned int)f2bf(acc[1]) << 16);
        st.y = (unsigned int)f2bf(acc[2]) | ((unsigned int)f2bf(acc[3]) << 16);
        st.z = (unsigned int)f2bf(acc[4]) | ((unsigned int)f2bf(acc[5]) << 16);
        st.w = (unsigned int)f2bf(acc[6]) | ((unsigned int)f2bf(acc[7]) << 16);
        *(uint4*)(out16 + (size_t)node * HD + cl * 8) = st;
    }
}

// ---- GRU gates: 32-row blocks, col-split waves, B in regs, dense staging/writeback ----
// bound (256,5): VGPR cap 102, kernel uses 48 — NO spills. (256,6) made the compiler
// allocate 40 VGPR + scratch spills: FETCH 59->83, WRITE 105->146, dur 70->97 (R14).
__global__ __launch_bounds__(256, 5) void k_gru_gates(
    const unsigned short* __restrict__ m_bf, const unsigned short* __restrict__ g_bf,
    const unsigned short* __restrict__ Wih, const unsigned short* __restrict__ Whh,
    const float* __restrict__ b_ih, const float* __restrict__ b_hh,
    unsigned short* __restrict__ g16_out, int M)
{
    __shared__ unsigned short sh[2 * 32 * LDST];   // 17408 B; reused as fp32 stage
    unsigned short* Am = sh;
    unsigned short* Ag = sh + 32 * LDST;
    const int tid = threadIdx.x;
    const int r0 = blockIdx.x * 32;
    // dense flat staging: per instruction 256 threads x 16 B contiguous
    #pragma unroll
    for (int it = 0; it < 2; it++) {
        int idx = it * 2048 + tid * 8;   // ushort index in 32x128 tile
        int rowi = idx >> 7, c = idx & 127;
        int gr = r0 + rowi; if (gr >= M) gr = M - 1;
        *(float4*)(Am + rowi * LDST + c) = *(const float4*)(m_bf + (size_t)gr * HD + c);
        *(float4*)(Ag + rowi * LDST + c) = *(const float4*)(g_bf + (size_t)gr * HD + c);
    }
    __syncthreads();
    const int w = tid >> 6, l = tid & 63;
    const int m16 = l & 15, quad = l >> 4;

    floatx4 accA[2][2], accB[2][2];
    bf16x8 bf[2][4];
    #pragma unroll
    for (int rg = 0; rg < 2; rg++)
        #pragma unroll
        for (int c = 0; c < 2; c++) {
            accA[rg][c] = (floatx4){0.f, 0.f, 0.f, 0.f};
            accB[rg][c] = (floatx4){0.f, 0.f, 0.f, 0.f};
        }
    // r-gate: accA = m@Wih_r + g@Whh_r
    loadB(Wih, w, m16, quad, bf);
    mmAcc32(Am, m16, quad, bf, accA);
    loadB(Whh, w, m16, quad, bf);
    mmAcc32(Ag, m16, quad, bf, accA);
    // hn: accB = g@Whh_n
    loadB(Whh + 256 * HD, w, m16, quad, bf);
    mmAcc32(Ag, m16, quad, bf, accB);
    // fold: accB = sigm(r)*(hn + b_hhn)
    #pragma unroll
    for (int cgl = 0; cgl < 2; cgl++) {
        int c = (2 * w + cgl) * 16 + m16;
        float br = b_ih[c] + b_hh[c];
        float bhn = b_hh[256 + c];
        #pragma unroll
        for (int rg = 0; rg < 2; rg++)
            #pragma unroll
            for (int i = 0; i < 4; i++) {
                float r = sigm(accA[rg][cgl][i] + br);
                accB[rg][cgl][i] = r * (accB[rg][cgl][i] + bhn);
            }
    }
    // accB += m@Wih_n
    loadB(Wih + 256 * HD, w, m16, quad, bf);
    mmAcc32(Am, m16, quad, bf, accB);
    // z: accA = m@Wih_z + g@Whh_z
    #pragma unroll
    for (int rg = 0; rg < 2; rg++)
        #pragma unroll
        for (int c = 0; c < 2; c++) accA[rg][c] = (floatx4){0.f, 0.f, 0.f, 0.f};
    loadB(Wih + 128 * HD, w, m16, quad, bf);
    mmAcc32(Am, m16, quad, bf, accA);
    loadB(Whh + 128 * HD, w, m16, quad, bf);
    mmAcc32(Ag, m16, quad, bf, accA);
    // GRU update; old state from the bf16 Ag tile (no global traffic)
    float ov[2][2][4];
    #pragma unroll
    for (int cgl = 0; cgl < 2; cgl++) {
        int c = (2 * w + cgl) * 16 + m16;
        float bz = b_ih[128 + c] + b_hh[128 + c];
        float bin = b_ih[256 + c];
        #pragma unroll
        for (int rg = 0; rg < 2; rg++)
            #pragma unroll
            for (int i = 0; i < 4; i++) {
                float z = sigm(accA[rg][cgl][i] + bz);
                float n = tanhf(accB[rg][cgl][i] + bin);
                float gv = bf2f(Ag[(rg * 16 + quad * 4 + i) * LDST + c]);
                ov[cgl][rg][i] = (1.f - z) * n + z * gv;
            }
    }
    __syncthreads();   // Am/Ag dead; reuse as 32 x FST fp32 staging
    float* shf = (float*)sh;
    #pragma unroll
    for (int cgl = 0; cgl < 2; cgl++) {
        int c = (2 * w + cgl) * 16 + m16;
        #pragma unroll
        for (int rg = 0; rg < 2; rg++)
            #pragma unroll
            for (int i = 0; i < 4; i++)
                shf[(rg * 16 + quad * 4 + i) * FST + c] = ov[cgl][rg][i];
    }
    __syncthreads();
    // dense packed writeback: per instruction 256 threads x 16 B contiguous
    #pragma unroll
    for (int it = 0; it < 2; it++) {
        int idx = it * 2048 + tid * 8;
        int rowi = idx >> 7, c = idx & 127;
        int gr = r0 + rowi;
        if (gr < M) {
            float4 v0 = *(const float4*)(shf + rowi * FST + c);
            float4 v1 = *(const float4*)(shf + rowi * FST + c + 4);
            uint4 st;
            st.x = (unsigned int)f2bf(v0.x) | ((unsigned int)f2bf(v0.y) << 16);
            st.y = (unsigned int)f2bf(v0.z) | ((unsigned int)f2bf(v0.w) << 16);
            st.z = (unsigned int)f2bf(v1.x) | ((unsigned int)f2bf(v1.y) << 16);
            st.w = (unsigned int)f2bf(v1.z) | ((unsigned int)f2bf(v1.w) << 16);
            *(uint4*)(g16_out + (size_t)gr * HD + c) = st;
        }
    }
}

// ---- fused head: h2=leaky(g_bf)+h ; h3=leaky(h2@W1+b1) ; probs=sigm(h3.W2+b2) ----
__global__ __launch_bounds__(256, 4) void k_head_fused(
    const unsigned short* __restrict__ g_bf, const float* __restrict__ h,
    const unsigned short* __restrict__ W1T, const float* __restrict__ b1,
    const float* __restrict__ W2, const float* __restrict__ b2,
    float* __restrict__ probs, int M)
{
    __shared__ unsigned short As[64 * LDST];
    const int tid = threadIdx.x;
    const int r0 = blockIdx.x * 64;
    {
        int rowi = tid >> 2, q = tid & 3;
        int gr = r0 + rowi; if (gr >= M) gr = M - 1;
        const unsigned short* gp = g_bf + (size_t)gr * HD + q * 32;
        const float* hp = h + (size_t)gr * HD + q * 32;
        unsigned short* dst = As + rowi * LDST + q * 32;
        #pragma unroll
        for (int i = 0; i < 32; i += 4) {
            ushort4 gu = *(const ushort4*)(gp + i);
            float4 hv = *(const float4*)(hp + i);
            ushort4 o;
            float v;
            v = bf2f(gu.x); v = v > 0.f ? v : v * NEG; o.x = f2bf(v + hv.x);
            v = bf2f(gu.y); v = v > 0.f ? v : v * NEG; o.y = f2bf(v + hv.y);
            v = bf2f(gu.z); v = v > 0.f ? v : v * NEG; o.z = f2bf(v + hv.z);
            v = bf2f(gu.w); v = v > 0.f ? v : v * NEG; o.w = f2bf(v + hv.w);
            *(ushort4*)(dst + i) = o;
        }
    }
    __syncthreads();
    const int w = tid >> 6, l = tid & 63;
    const int m16 = l & 15, quad = l >> 4;
    floatx4 acc[8];
    #pragma unroll
    for (int j = 0; j < 8; j++) acc[j] = (floatx4){0.f, 0.f, 0.f, 0.f};
    mm64(As + (w * 16 + m16) * LDST, W1T, m16, quad, acc);
    #pragma unroll
    for (int i = 0; i < 4; i++) {
        float s = 0.f;
        #pragma unroll
        for (int cg = 0; cg < 8; cg++) {
            int c = cg * 16 + m16;
            float v = acc[cg][i] + b1[c];
            v = v > 0.f ? v : v * NEG;
            s += v * W2[c];
        }
        s += __shfl_xor(s, 1); s += __shfl_xor(s, 2);
        s += __shfl_xor(s, 4); s += __shfl_xor(s, 8);
        int r = r0 + w * 16 + quad * 4 + i;
        if (m16 == 0 && r < M) probs[r] = sigm(s + b2[0]);
    }
}

// ---- weight prep ----
__global__ void k_prep_w(const float* __restrict__ W_gcn, const float* __restrict__ W_gg,
                         const float* __restrict__ W_ih, const float* __restrict__ W_hh,
                         const float* __restrict__ W1, unsigned short* __restrict__ Wq) {
    int i = blockIdx.x * blockDim.x + threadIdx.x;
    if (i >= 180224) return;
    float v;
    if (i < 16384) {
        int n = i >> 7, k = i & 127;
        v = W_gcn[k * 128 + n];
    } else if (i < 65536) {
        int j = i - 16384;
        int l = j >> 14, rr = j & 16383;
        int n = rr >> 7, k = rr & 127;
        v = W_gg[l * 16384 + k * 128 + n];
    } else if (i < 114688) {
        v = W_ih[i - 65536];
    } else if (i < 163840) {
        v = W_hh[i - 114688];
    } else {
        int j = i - 163840;
        int n = j >> 7, k = j & 127;
        v = W1[k * 128 + n];
    }
    Wq[i] = f2bf(v);
}

__global__ void k_cast_x(const float* __restrict__ s, unsigned short* __restrict__ d, int n2) {
    int i = blockIdx.x * blockDim.x + threadIdx.x;
    if (i >= n2) return;
    float2 v = *(const float2*)(s + (size_t)i * 2);
    unsigned int p = (unsigned int)f2bf(v.x) | ((unsigned int)f2bf(v.y) << 16);
    *(unsigned int*)(d + (size_t)i * 2) = p;
}

// ---- CSR build (4-way sharded histogram) ----
__global__ void k_hist(const int* __restrict__ col, int* __restrict__ cnt4,
                       int* __restrict__ rank, int N, int E) {
    int e = blockIdx.x * blockDim.x + threadIdx.x;
    if (e < E) {
        int s = blockIdx.x & 3;
        rank[e] = atomicAdd(&cnt4[s * N + col[e]], 1);
    }
}

#define SCHUNK 2048
__global__ __launch_bounds__(256) void k_scan1(const int* __restrict__ cnt4,
                                               int* __restrict__ excl,
                                               int* __restrict__ bsum, int N) {
    __shared__ int ts[256];
    int t = threadIdx.x;
    int base = blockIdx.x * SCHUNK + t * 8;
    int v[8]; int s = 0;
    #pragma unroll
    for (int q = 0; q < 8; q++) {
        int i = base + q;
        v[q] = (i < N) ? (cnt4[i] + cnt4[N + i] + cnt4[2 * N + i] + cnt4[3 * N + i]) : 0;
        s += v[q];
    }
    ts[t] = s;
    __syncthreads();
    for (int off = 1; off < 256; off <<= 1) {
        int a = (t >= off) ? ts[t - off] : 0;
        __syncthreads();
        ts[t] += a;
        __syncthreads();
    }
    int run = ts[t] - s;
    #pragma unroll
    for (int q = 0; q < 8; q++) { int i = base + q; if (i < N) excl[i] = run; run += v[q]; }
    if (t == 255) bsum[blockIdx.x] = ts[255];
}

__global__ void k_scan2(int* bsum, int nb) {
    if (threadIdx.x == 0) {
        int run = 0;
        for (int b = 0; b < nb; b++) { int v = bsum[b]; bsum[b] = run; run += v; }
    }
}

__global__ void k_csrfin(const int* __restrict__ excl, const int* __restrict__ bsum,
                         const int* __restrict__ cnt4, int* __restrict__ offs,
                         int* __restrict__ sbase, float* __restrict__ dinv, int N, int E) {
    int i = blockIdx.x * blockDim.x + threadIdx.x;
    if (i >= N) return;
    int o = excl[i] + bsum[i >> 11];
    offs[i] = o;
    if (i == 0) offs[N] = E;
    int c0 = cnt4[i], c1 = cnt4[N + i], c2 = cnt4[2 * N + i], c3 = cnt4[3 * N + i];
    sbase[i] = o;
    sbase[N + i] = o + c0;
    sbase[2 * N + i] = o + c0 + c1;
    sbase[3 * N + i] = o + c0 + c1 + c2;
    dinv[i] = rsqrtf((float)(c0 + c1 + c2 + c3) + 1.f);
}

__global__ void k_fill(const int* __restrict__ row, const int* __restrict__ col,
                       const int* __restrict__ sbase, const int* __restrict__ rank,
                       int* __restrict__ csr_rows, int N, int E) {
    int e = blockIdx.x * blockDim.x + threadIdx.x;
    if (e >= E) return;
    int s = (e >> 8) & 3;   // matches k_hist's blockIdx&3 (blockDim=256)
    csr_rows[sbase[s * N + col[e]] + rank[e]] = row[e];
}

// ---- maxcut loss over edges ----
__global__ __launch_bounds__(256) void k_loss_edge(const float* __restrict__ probs,
                                                   const int* __restrict__ row,
                                                   const int* __restrict__ col,
                                                   const int* __restrict__ batch,
                                                   float* __restrict__ ed,
                                                   float* __restrict__ ew, int E) {
    __shared__ float bd[GD], be[GD];
    if (threadIdx.x < GD) { bd[threadIdx.x] = 0.f; be[threadIdx.x] = 0.f; }
    __syncthreads();
    for (int e = blockIdx.x * blockDim.x + threadIdx.x; e < E; e += gridDim.x * blockDim.x) {
        int r = row[e];
        float pr = probs[r];
        int b = batch[r];
        atomicAdd(&bd[b], pr);
        atomicAdd(&be[b], pr * probs[col[e]]);
    }
    __syncthreads();
    if (threadIdx.x < GD) {
        atomicAdd(&ed[threadIdx.x], bd[threadIdx.x]);
        atomicAdd(&ew[threadIdx.x], be[threadIdx.x]);
    }
}

__global__ void k_finalize(const float* __restrict__ ed, const float* __restrict__ ew,
                           float* __restrict__ out) {
    int g = threadIdx.x;
    if (g < GD) out[g] = -(ed[g] - ew[g]) * 0.5f;
}

extern "C" void kernel_launch(void* const* d_in, const int* in_sizes, int n_in,
                              void* d_out, int out_size, void* d_ws, size_t ws_size,
                              hipStream_t stream) {
    const float* x     = (const float*)d_in[0];
    const int*   ei    = (const int*)d_in[1];
    const int*   batch = (const int*)d_in[2];
    const float* W_gcn = (const float*)d_in[3];
    const float* b_gcn = (const float*)d_in[4];
    const float* W_gg  = (const float*)d_in[5];
    const float* W_ih  = (const float*)d_in[6];
    const float* W_hh  = (const float*)d_in[7];
    const float* b_ih  = (const float*)d_in[8];
    const float* b_hh  = (const float*)d_in[9];
    const float* W1    = (const float*)d_in[10];
    const float* b1    = (const float*)d_in[11];
    const float* W2    = (const float*)d_in[12];
    const float* b2    = (const float*)d_in[13];
    float* out = (float*)d_out;

    const int N = in_sizes[2];
    const int E = in_sizes[1] / 2;
    const int* row = ei;
    const int* col = ei + E;
    const size_t NH = (size_t)N * HD;

    float* F = (float*)d_ws;
    float* f_h  = F + 0 * NH;
    float* f_xw = F + 1 * NH;
    unsigned short* U = (unsigned short*)(F + 2 * NH);
    unsigned short* x_bf  = U;
    unsigned short* g_bf  = U + 1 * NH;
    unsigned short* t_bf  = U + 2 * NH;
    unsigned short* m_bf  = U + 3 * NH;
    unsigned short* Wq    = U + 4 * NH;
    unsigned short* WgcnT = Wq;               // 16384
    unsigned short* WggT  = Wq + 16384;       // 3*16384
    unsigned short* Wih16 = Wq + 65536;       // 49152
    unsigned short* Whh16 = Wq + 114688;      // 49152
    unsigned short* W1T   = Wq + 163840;      // 16384
    float* S = (float*)(Wq + 180224);
    float* f_dinv  = S;
    float* f_probs = S + N;
    float* f_ed    = S + 2 * N;
    float* f_ew    = f_ed + GD;
    int* I = (int*)(f_ew + GD);
    int* i_cnt4  = I;                  // 4N (zeroed)
    int* i_excl  = I + 4 * N;          // N
    int* i_offs  = I + 5 * N;          // N+1
    int* i_bsum  = I + 6 * N + 8;      // <=64
    int* i_sbase = I + 6 * N + 128;    // 4N
    int* i_rank  = I + 10 * N + 128;   // E
    int* i_csr   = i_rank + E;         // E

    const int nb_scan = (N + SCHUNK - 1) / SCHUNK;
    const int gb32 = (N + 31) / 32;
    const int gb64 = (N + 63) / 64;
    const int gb128 = (N + 127) / 128;
    const int eg = (E + 255) / 256;
    const int ng = (N + 255) / 256;
    const int gather_grid = (N + 3) / 4;

    hipMemsetAsync(i_cnt4, 0, sizeof(int) * 4 * (size_t)N, stream);
    hipMemsetAsync(f_ed, 0, sizeof(float) * 2 * GD, stream);

    // weight prep
    k_prep_w<<<704, 256, 0, stream>>>(W_gcn, W_gg, W_ih, W_hh, W1, Wq);
    k_cast_x<<<(int)((NH / 2 + 255) / 256), 256, 0, stream>>>(x, x_bf, (int)(NH / 2));

    // CSR build
    k_hist<<<eg, 256, 0, stream>>>(col, i_cnt4, i_rank, N, E);
    k_scan1<<<nb_scan, 256, 0, stream>>>(i_cnt4, i_excl, i_bsum, N);
    k_scan2<<<1, 64, 0, stream>>>(i_bsum, nb_scan);
    k_csrfin<<<ng, 256, 0, stream>>>(i_excl, i_bsum, i_cnt4, i_offs, i_sbase, f_dinv, N, E);
    k_fill<<<eg, 256, 0, stream>>>(row, col, i_sbase, i_rank, i_csr, N, E);

    // GCN: xw = x@W_gcn (fp32+bf16); gather+finish -> h fp32, g bf16
    gemm_mfma<<<gb128, 256, 0, stream>>>(x_bf, WgcnT, f_xw, t_bf, N);
    k_gather_gcn<<<gather_grid, 256, 0, stream>>>(t_bf, f_xw, i_csr, i_offs, f_dinv,
                                                  b_gcn, f_h, g_bf, N);

    // GatedGraphConv layers: project -> parallel gather -> 32-row gates+GRU (bf16 state)
    for (int l = 0; l < 3; l++) {
        gemm_mfma<<<gb128, 256, 0, stream>>>(g_bf, WggT + (size_t)l * 16384,
                                             nullptr, t_bf, N);
        k_gather_m<<<gather_grid, 256, 0, stream>>>(t_bf, i_csr, i_offs, m_bf, N);
        k_gru_gates<<<gb32, 256, 0, stream>>>(m_bf, g_bf, Wih16, Whh16, b_ih, b_hh,
                                              g_bf, N);
    }

    // fused head (reads bf16 g state + fp32 h)
    k_head_fused<<<gb64, 256, 0, stream>>>(g_bf, f_h, W1T, b1, W2, b2, f_probs, N);

    // maxcut loss (expected_degree folded into edge pass — exact identity)
    k_loss_edge<<<1024, 256, 0, stream>>>(f_probs, row, col, batch, f_ed, f_ew, E);
    k_finalize<<<1, 64, 0, stream>>>(f_ed, f_ew, out);
}

// Round 16
// 574.242 us; speedup vs baseline: 1.1037x; 1.0216x over previous
//
#include <hip/hip_runtime.h>
#include <math.h>

#define HD 128
#define NEG 0.01f
#define GD 64
#define LDST 136   // LDS row stride in ushorts
#define FST 132    // fp32 staging stride (2-way-free scatter)

typedef short bf16x8 __attribute__((ext_vector_type(8)));
typedef float floatx4 __attribute__((ext_vector_type(4)));

__device__ __forceinline__ unsigned short f2bf(float f) {
    unsigned int u = __float_as_uint(f);
    u += 0x7fffu + ((u >> 16) & 1u);   // RNE
    return (unsigned short)(u >> 16);
}
__device__ __forceinline__ float bf2f(unsigned short b) {
    return __uint_as_float(((unsigned int)b) << 16);
}
__device__ __forceinline__ float sigm(float v) { return 1.f / (1.f + __expf(-v)); }
__device__ __forceinline__ float fast_tanh(float v) { return 2.f / (1.f + __expf(-2.f * v)) - 1.f; }

// row-split helper (used by head): A row from LDS, B streamed
__device__ __forceinline__ void mm64(const unsigned short* __restrict__ ap,
                                     const unsigned short* __restrict__ W,
                                     int m16, int quad, floatx4* acc) {
    #pragma unroll
    for (int ks = 0; ks < 4; ks++) {
        const int koff = ks * 32 + quad * 8;
        bf16x8 a = *(const bf16x8*)(ap + koff);
        #pragma unroll
        for (int cg = 0; cg < 8; cg++) {
            bf16x8 b = *(const bf16x8*)(W + (size_t)(cg * 16 + m16) * HD + koff);
            acc[cg] = __builtin_amdgcn_mfma_f32_16x16x32_bf16(a, b, acc[cg], 0, 0, 0);
        }
    }
}

// column-split helpers: wave owns 2 col-groups, B in registers
__device__ __forceinline__ void loadB(const unsigned short* __restrict__ W,
                                      int w, int m16, int quad, bf16x8 bf[2][4]) {
    #pragma unroll
    for (int cgl = 0; cgl < 2; cgl++)
        #pragma unroll
        for (int ks = 0; ks < 4; ks++)
            bf[cgl][ks] = *(const bf16x8*)(W + (size_t)((2 * w + cgl) * 16 + m16) * HD
                                           + ks * 32 + quad * 8);
}
// 32-row tile: 2 row-groups
__device__ __forceinline__ void mmAcc32(const unsigned short* __restrict__ Atile,
                                        int m16, int quad, const bf16x8 bf[2][4],
                                        floatx4 acc[2][2]) {
    #pragma unroll
    for (int rg = 0; rg < 2; rg++)
        #pragma unroll
        for (int ks = 0; ks < 4; ks++) {
            bf16x8 a = *(const bf16x8*)(Atile + (rg * 16 + m16) * LDST + ks * 32 + quad * 8);
            acc[rg][0] = __builtin_amdgcn_mfma_f32_16x16x32_bf16(a, bf[0][ks], acc[rg][0], 0, 0, 0);
            acc[rg][1] = __builtin_amdgcn_mfma_f32_16x16x32_bf16(a, bf[1][ks], acc[rg][1], 0, 0, 0);
        }
}

// ---- plain MFMA GEMM: C = A_bf[M x 128] @ BT_bf[128 x 128]^T; dense C16 epilogue ----
__global__ __launch_bounds__(256) void gemm_mfma(
    const unsigned short* __restrict__ A, const unsigned short* __restrict__ BT,
    float* __restrict__ C32, unsigned short* __restrict__ C16, int M)
{
    __shared__ unsigned short As[128 * LDST];
    __shared__ unsigned short Bs[128 * LDST];
    const int tid = threadIdx.x;
    const int r0 = blockIdx.x * 128;
    {
        int rowi = tid >> 1, half = tid & 1;
        int gr = r0 + rowi; if (gr >= M) gr = M - 1;
        const float4* sa = (const float4*)(A + (size_t)gr * HD + half * 64);
        float4* da = (float4*)(As + rowi * LDST + half * 64);
        const float4* sb = (const float4*)(BT + (size_t)rowi * HD + half * 64);
        float4* db = (float4*)(Bs + rowi * LDST + half * 64);
        #pragma unroll
        for (int i = 0; i < 8; i++) { da[i] = sa[i]; db[i] = sb[i]; }
    }
    __syncthreads();
    const int wave = tid >> 6, lane = tid & 63;
    const int m16 = lane & 15, quad = lane >> 4;
    floatx4 acc[2][8];
    #pragma unroll
    for (int i = 0; i < 2; i++)
        #pragma unroll
        for (int j = 0; j < 8; j++) acc[i][j] = (floatx4){0.f, 0.f, 0.f, 0.f};
    const unsigned short* ar0 = As + (wave * 32 + m16) * LDST;
    const unsigned short* ar1 = As + (wave * 32 + 16 + m16) * LDST;
    #pragma unroll
    for (int ks = 0; ks < 4; ks++) {
        const int koff = ks * 32 + quad * 8;
        bf16x8 a0 = *(const bf16x8*)(ar0 + koff);
        bf16x8 a1 = *(const bf16x8*)(ar1 + koff);
        #pragma unroll
        for (int cg = 0; cg < 8; cg++) {
            bf16x8 b = *(const bf16x8*)(Bs + (cg * 16 + m16) * LDST + koff);
            acc[0][cg] = __builtin_amdgcn_mfma_f32_16x16x32_bf16(a0, b, acc[0][cg], 0, 0, 0);
            acc[1][cg] = __builtin_amdgcn_mfma_f32_16x16x32_bf16(a1, b, acc[1][cg], 0, 0, 0);
        }
    }
    // C32 path (only first gemm): 64 B-dense per 16 lanes — keep direct
    if (C32) {
        #pragma unroll
        for (int rg = 0; rg < 2; rg++)
            #pragma unroll
            for (int cg = 0; cg < 8; cg++)
                #pragma unroll
                for (int i = 0; i < 4; i++) {
                    int r = r0 + wave * 32 + rg * 16 + quad * 4 + i;
                    if (r < M) C32[(size_t)r * HD + cg * 16 + m16] = acc[rg][cg][i];
                }
    }
    __syncthreads();   // all waves done reading As/Bs
    // stage bf16 C into As (dead), then dense sweep
    #pragma unroll
    for (int rg = 0; rg < 2; rg++)
        #pragma unroll
        for (int cg = 0; cg < 8; cg++)
            #pragma unroll
            for (int i = 0; i < 4; i++)
                As[(wave * 32 + rg * 16 + quad * 4 + i) * LDST + cg * 16 + m16] =
                    f2bf(acc[rg][cg][i]);
    __syncthreads();
    #pragma unroll
    for (int it = 0; it < 8; it++) {
        int idx = it * 2048 + tid * 8;       // ushort index into 128x128 tile
        int rowi = idx >> 7, c = idx & 127;
        int gr = r0 + rowi;
        if (gr < M) {
            uint4 v = *(const uint4*)(As + rowi * LDST + c);
            *(uint4*)(C16 + (size_t)gr * HD + c) = v;
        }
    }
}

// ---- GCN gather+finish (16B/lane: 4 edges per wave-load): h fp32, g bf16 ----
__global__ __launch_bounds__(256) void k_gather_gcn(
    const unsigned short* __restrict__ src, const float* __restrict__ xw,
    const int* __restrict__ csr, const int* __restrict__ offs,
    const float* __restrict__ dinv, const float* __restrict__ bias,
    float* __restrict__ h, unsigned short* __restrict__ g16, int N)
{
    int node = blockIdx.x * 4 + (threadIdx.x >> 6);
    if (node >= N) return;
    int lane = threadIdx.x & 63;
    int sub = lane >> 4, cl = lane & 15;
    int s = offs[node], e = offs[node + 1];
    float acc[8] = {0.f, 0.f, 0.f, 0.f, 0.f, 0.f, 0.f, 0.f};
    int j = s;
    for (; j + 8 <= e; j += 8) {
        int ra = csr[j + sub], rb = csr[j + 4 + sub];
        float sa = dinv[ra], sb = dinv[rb];
        bf16x8 va = *(const bf16x8*)(src + (size_t)ra * HD + cl * 8);
        bf16x8 vb = *(const bf16x8*)(src + (size_t)rb * HD + cl * 8);
        #pragma unroll
        for (int q = 0; q < 8; q++)
            acc[q] += bf2f((unsigned short)va[q]) * sa + bf2f((unsigned short)vb[q]) * sb;
    }
    for (; j < e; j += 4) {
        int jj = j + sub;
        if (jj < e) {
            int r = csr[jj];
            float sc = dinv[r];
            bf16x8 v = *(const bf16x8*)(src + (size_t)r * HD + cl * 8);
            #pragma unroll
            for (int q = 0; q < 8; q++)
                acc[q] += bf2f((unsigned short)v[q]) * sc;
        }
    }
    #pragma unroll
    for (int q = 0; q < 8; q++) {
        acc[q] += __shfl_xor(acc[q], 16);
        acc[q] += __shfl_xor(acc[q], 32);
    }
    if (sub == 0) {
        float dn = dinv[node], dv2 = dn * dn;
        size_t base = (size_t)node * HD + cl * 8;
        float4 xv0 = *(const float4*)(xw + base);
        float4 xv1 = *(const float4*)(xw + base + 4);
        float xs[8] = {xv0.x, xv0.y, xv0.z, xv0.w, xv1.x, xv1.y, xv1.z, xv1.w};
        float o[8];
        #pragma unroll
        for (int q = 0; q < 8; q++) {
            float v = acc[q] * dn + xs[q] * dv2 + bias[cl * 8 + q];
            o[q] = v > 0.f ? v : v * NEG;
        }
        *(float4*)(h + base) = (float4){o[0], o[1], o[2], o[3]};
        *(float4*)(h + base + 4) = (float4){o[4], o[5], o[6], o[7]};
        uint4 st;
        st.x = (unsigned int)f2bf(o[0]) | ((unsigned int)f2bf(o[1]) << 16);
        st.y = (unsigned int)f2bf(o[2]) | ((unsigned int)f2bf(o[3]) << 16);
        st.z = (unsigned int)f2bf(o[4]) | ((unsigned int)f2bf(o[5]) << 16);
        st.w = (unsigned int)f2bf(o[6]) | ((unsigned int)f2bf(o[7]) << 16);
        *(uint4*)(g16 + base) = st;
    }
}

// ---- layer gather (16B/lane: 4 edges per wave-load), bf16 in/out ----
__global__ __launch_bounds__(256) void k_gather_m(
    const unsigned short* __restrict__ src, const int* __restrict__ csr,
    const int* __restrict__ offs, unsigned short* __restrict__ out16, int N)
{
    int node = blockIdx.x * 4 + (threadIdx.x >> 6);
    if (node >= N) return;
    int lane = threadIdx.x & 63;
    int sub = lane >> 4, cl = lane & 15;
    int s = offs[node], e = offs[node + 1];
    float acc[8] = {0.f, 0.f, 0.f, 0.f, 0.f, 0.f, 0.f, 0.f};
    int j = s;
    for (; j + 8 <= e; j += 8) {
        int ra = csr[j + sub], rb = csr[j + 4 + sub];
        bf16x8 va = *(const bf16x8*)(src + (size_t)ra * HD + cl * 8);
        bf16x8 vb = *(const bf16x8*)(src + (size_t)rb * HD + cl * 8);
        #pragma unroll
        for (int q = 0; q < 8; q++)
            acc[q] += bf2f((unsigned short)va[q]) + bf2f((unsigned short)vb[q]);
    }
    for (; j < e; j += 4) {
        int jj = j + sub;
        if (jj < e) {
            int r = csr[jj];
            bf16x8 v = *(const bf16x8*)(src + (size_t)r * HD + cl * 8);
            #pragma unroll
            for (int q = 0; q < 8; q++)
                acc[q] += bf2f((unsigned short)v[q]);
        }
    }
    #pragma unroll
    for (int q = 0; q < 8; q++) {
        acc[q] += __shfl_xor(acc[q], 16);
        acc[q] += __shfl_xor(acc[q], 32);
    }
    if (sub == 0) {
        uint4 st;
        st.x = (unsigned int)f2bf(acc[0]) | ((unsigned int)f2bf(acc[1]) << 16);
        st.y = (unsigned int)f2bf(acc[2]) | ((unsigned int)f2bf(acc[3]) << 16);
        st.z = (unsigned int)f2bf(acc[4]) | ((unsigned int)f2bf(acc[5]) << 16);
        st.w = (unsigned int)f2bf(acc[6]) | ((unsigned int)f2bf(acc[7]) << 16);
        *(uint4*)(out16 + (size_t)node * HD + cl * 8) = st;
    }
}

// ---- GRU gates: 32-row blocks, col-split waves, double-buffered B prefetch ----
// bound (256,5): measured no-spill config (VGPR 48 + ~32 dbuf; cap 102).
__global__ __launch_bounds__(256, 5) void k_gru_gates(
    const unsigned short* __restrict__ m_bf, const unsigned short* __restrict__ g_bf,
    const unsigned short* __restrict__ Wih, const unsigned short* __restrict__ Whh,
    const float* __restrict__ b_ih, const float* __restrict__ b_hh,
    unsigned short* __restrict__ g16_out, int M)
{
    __shared__ unsigned short sh[2 * 32 * LDST];   // 17408 B; reused as fp32 stage
    unsigned short* Am = sh;
    unsigned short* Ag = sh + 32 * LDST;
    const int tid = threadIdx.x;
    const int r0 = blockIdx.x * 32;
    // dense flat staging: per instruction 256 threads x 16 B contiguous
    #pragma unroll
    for (int it = 0; it < 2; it++) {
        int idx = it * 2048 + tid * 8;   // ushort index in 32x128 tile
        int rowi = idx >> 7, c = idx & 127;
        int gr = r0 + rowi; if (gr >= M) gr = M - 1;
        *(float4*)(Am + rowi * LDST + c) = *(const float4*)(m_bf + (size_t)gr * HD + c);
        *(float4*)(Ag + rowi * LDST + c) = *(const float4*)(g_bf + (size_t)gr * HD + c);
    }
    __syncthreads();
    const int w = tid >> 6, l = tid & 63;
    const int m16 = l & 15, quad = l >> 4;

    floatx4 accA[2][2], accB[2][2];
    bf16x8 bfA[2][4], bfB[2][4];
    #pragma unroll
    for (int rg = 0; rg < 2; rg++)
        #pragma unroll
        for (int c = 0; c < 2; c++) {
            accA[rg][c] = (floatx4){0.f, 0.f, 0.f, 0.f};
            accB[rg][c] = (floatx4){0.f, 0.f, 0.f, 0.f};
        }
    // software-pipelined: load(i+1) in flight while mmAcc(i) runs
    loadB(Wih, w, m16, quad, bfA);                 // Wih_r
    loadB(Whh, w, m16, quad, bfB);                 // Whh_r
    mmAcc32(Am, m16, quad, bfA, accA);             // r += m@Wih_r
    loadB(Whh + 256 * HD, w, m16, quad, bfA);      // Whh_n
    mmAcc32(Ag, m16, quad, bfB, accA);             // r += g@Whh_r
    loadB(Wih + 256 * HD, w, m16, quad, bfB);      // Wih_n
    mmAcc32(Ag, m16, quad, bfA, accB);             // hn = g@Whh_n
    // fold: accB = sigm(r)*(hn + b_hhn)   (Wih_n load still in flight)
    #pragma unroll
    for (int cgl = 0; cgl < 2; cgl++) {
        int c = (2 * w + cgl) * 16 + m16;
        float br = b_ih[c] + b_hh[c];
        float bhn = b_hh[256 + c];
        #pragma unroll
        for (int rg = 0; rg < 2; rg++)
            #pragma unroll
            for (int i = 0; i < 4; i++) {
                float r = sigm(accA[rg][cgl][i] + br);
                accB[rg][cgl][i] = r * (accB[rg][cgl][i] + bhn);
            }
    }
    loadB(Wih + 128 * HD, w, m16, quad, bfA);      // Wih_z
    mmAcc32(Am, m16, quad, bfB, accB);             // += m@Wih_n
    loadB(Whh + 128 * HD, w, m16, quad, bfB);      // Whh_z
    #pragma unroll
    for (int rg = 0; rg < 2; rg++)
        #pragma unroll
        for (int c = 0; c < 2; c++) accA[rg][c] = (floatx4){0.f, 0.f, 0.f, 0.f};
    mmAcc32(Am, m16, quad, bfA, accA);             // z += m@Wih_z
    mmAcc32(Ag, m16, quad, bfB, accA);             // z += g@Whh_z
    // GRU update; old state from the bf16 Ag tile (no global traffic)
    float ov[2][2][4];
    #pragma unroll
    for (int cgl = 0; cgl < 2; cgl++) {
        int c = (2 * w + cgl) * 16 + m16;
        float bz = b_ih[128 + c] + b_hh[128 + c];
        float bin = b_ih[256 + c];
        #pragma unroll
        for (int rg = 0; rg < 2; rg++)
            #pragma unroll
            for (int i = 0; i < 4; i++) {
                float z = sigm(accA[rg][cgl][i] + bz);
                float n = fast_tanh(accB[rg][cgl][i] + bin);
                float gv = bf2f(Ag[(rg * 16 + quad * 4 + i) * LDST + c]);
                ov[cgl][rg][i] = (1.f - z) * n + z * gv;
            }
    }
    __syncthreads();   // Am/Ag dead; reuse as 32 x FST fp32 staging
    float* shf = (float*)sh;
    #pragma unroll
    for (int cgl = 0; cgl < 2; cgl++) {
        int c = (2 * w + cgl) * 16 + m16;
        #pragma unroll
        for (int rg = 0; rg < 2; rg++)
            #pragma unroll
            for (int i = 0; i < 4; i++)
                shf[(rg * 16 + quad * 4 + i) * FST + c] = ov[cgl][rg][i];
    }
    __syncthreads();
    // dense packed writeback: per instruction 256 threads x 16 B contiguous
    #pragma unroll
    for (int it = 0; it < 2; it++) {
        int idx = it * 2048 + tid * 8;
        int rowi = idx >> 7, c = idx & 127;
        int gr = r0 + rowi;
        if (gr < M) {
            float4 v0 = *(const float4*)(shf + rowi * FST + c);
            float4 v1 = *(const float4*)(shf + rowi * FST + c + 4);
            uint4 st;
            st.x = (unsigned int)f2bf(v0.x) | ((unsigned int)f2bf(v0.y) << 16);
            st.y = (unsigned int)f2bf(v0.z) | ((unsigned int)f2bf(v0.w) << 16);
            st.z = (unsigned int)f2bf(v1.x) | ((unsigned int)f2bf(v1.y) << 16);
            st.w = (unsigned int)f2bf(v1.z) | ((unsigned int)f2bf(v1.w) << 16);
            *(uint4*)(g16_out + (size_t)gr * HD + c) = st;
        }
    }
}

// ---- fused head: h2=leaky(g_bf)+h ; h3=leaky(h2@W1+b1) ; probs=sigm(h3.W2+b2) ----
__global__ __launch_bounds__(256, 4) void k_head_fused(
    const unsigned short* __restrict__ g_bf, const float* __restrict__ h,
    const unsigned short* __restrict__ W1T, const float* __restrict__ b1,
    const float* __restrict__ W2, const float* __restrict__ b2,
    float* __restrict__ probs, int M)
{
    __shared__ unsigned short As[64 * LDST];
    const int tid = threadIdx.x;
    const int r0 = blockIdx.x * 64;
    {
        int rowi = tid >> 2, q = tid & 3;
        int gr = r0 + rowi; if (gr >= M) gr = M - 1;
        const unsigned short* gp = g_bf + (size_t)gr * HD + q * 32;
        const float* hp = h + (size_t)gr * HD + q * 32;
        unsigned short* dst = As + rowi * LDST + q * 32;
        #pragma unroll
        for (int i = 0; i < 32; i += 4) {
            ushort4 gu = *(const ushort4*)(gp + i);
            float4 hv = *(const float4*)(hp + i);
            ushort4 o;
            float v;
            v = bf2f(gu.x); v = v > 0.f ? v : v * NEG; o.x = f2bf(v + hv.x);
            v = bf2f(gu.y); v = v > 0.f ? v : v * NEG; o.y = f2bf(v + hv.y);
            v = bf2f(gu.z); v = v > 0.f ? v : v * NEG; o.z = f2bf(v + hv.z);
            v = bf2f(gu.w); v = v > 0.f ? v : v * NEG; o.w = f2bf(v + hv.w);
            *(ushort4*)(dst + i) = o;
        }
    }
    __syncthreads();
    const int w = tid >> 6, l = tid & 63;
    const int m16 = l & 15, quad = l >> 4;
    floatx4 acc[8];
    #pragma unroll
    for (int j = 0; j < 8; j++) acc[j] = (floatx4){0.f, 0.f, 0.f, 0.f};
    mm64(As + (w * 16 + m16) * LDST, W1T, m16, quad, acc);
    #pragma unroll
    for (int i = 0; i < 4; i++) {
        float s = 0.f;
        #pragma unroll
        for (int cg = 0; cg < 8; cg++) {
            int c = cg * 16 + m16;
            float v = acc[cg][i] + b1[c];
            v = v > 0.f ? v : v * NEG;
            s += v * W2[c];
        }
        s += __shfl_xor(s, 1); s += __shfl_xor(s, 2);
        s += __shfl_xor(s, 4); s += __shfl_xor(s, 8);
        int r = r0 + w * 16 + quad * 4 + i;
        if (m16 == 0 && r < M) probs[r] = sigm(s + b2[0]);
    }
}

// ---- weight prep ----
__global__ void k_prep_w(const float* __restrict__ W_gcn, const float* __restrict__ W_gg,
                         const float* __restrict__ W_ih, const float* __restrict__ W_hh,
                         const float* __restrict__ W1, unsigned short* __restrict__ Wq) {
    int i = blockIdx.x * blockDim.x + threadIdx.x;
    if (i >= 180224) return;
    float v;
    if (i < 16384) {
        int n = i >> 7, k = i & 127;
        v = W_gcn[k * 128 + n];
    } else if (i < 65536) {
        int j = i - 16384;
        int l = j >> 14, rr = j & 16383;
        int n = rr >> 7, k = rr & 127;
        v = W_gg[l * 16384 + k * 128 + n];
    } else if (i < 114688) {
        v = W_ih[i - 65536];
    } else if (i < 163840) {
        v = W_hh[i - 114688];
    } else {
        int j = i - 163840;
        int n = j >> 7, k = j & 127;
        v = W1[k * 128 + n];
    }
    Wq[i] = f2bf(v);
}

__global__ void k_cast_x(const float* __restrict__ s, unsigned short* __restrict__ d, int n2) {
    int i = blockIdx.x * blockDim.x + threadIdx.x;
    if (i >= n2) return;
    float2 v = *(const float2*)(s + (size_t)i * 2);
    unsigned int p = (unsigned int)f2bf(v.x) | ((unsigned int)f2bf(v.y) << 16);
    *(unsigned int*)(d + (size_t)i * 2) = p;
}

// ---- CSR build (8-way sharded histogram) ----
__global__ void k_hist(const int* __restrict__ col, int* __restrict__ cnt8,
                       int* __restrict__ rank, int N, int E) {
    int e = blockIdx.x * blockDim.x + threadIdx.x;
    if (e < E) {
        int s = blockIdx.x & 7;
        rank[e] = atomicAdd(&cnt8[s * N + col[e]], 1);
    }
}

#define SCHUNK 2048
__global__ __launch_bounds__(256) void k_scan1(const int* __restrict__ cnt8,
                                               int* __restrict__ excl,
                                               int* __restrict__ bsum, int N) {
    __shared__ int ts[256];
    int t = threadIdx.x;
    int base = blockIdx.x * SCHUNK + t * 8;
    int v[8]; int s = 0;
    #pragma unroll
    for (int q = 0; q < 8; q++) {
        int i = base + q;
        int c = 0;
        if (i < N) {
            #pragma unroll
            for (int sh = 0; sh < 8; sh++) c += cnt8[(size_t)sh * N + i];
        }
        v[q] = c; s += c;
    }
    ts[t] = s;
    __syncthreads();
    for (int off = 1; off < 256; off <<= 1) {
        int a = (t >= off) ? ts[t - off] : 0;
        __syncthreads();
        ts[t] += a;
        __syncthreads();
    }
    int run = ts[t] - s;
    #pragma unroll
    for (int q = 0; q < 8; q++) { int i = base + q; if (i < N) excl[i] = run; run += v[q]; }
    if (t == 255) bsum[blockIdx.x] = ts[255];
}

__global__ void k_scan2(int* bsum, int nb) {
    if (threadIdx.x == 0) {
        int run = 0;
        for (int b = 0; b < nb; b++) { int v = bsum[b]; bsum[b] = run; run += v; }
    }
}

__global__ void k_csrfin(const int* __restrict__ excl, const int* __restrict__ bsum,
                         const int* __restrict__ cnt8, int* __restrict__ offs,
                         int* __restrict__ sbase, float* __restrict__ dinv, int N, int E) {
    int i = blockIdx.x * blockDim.x + threadIdx.x;
    if (i >= N) return;
    int o = excl[i] + bsum[i >> 11];
    offs[i] = o;
    if (i == 0) offs[N] = E;
    int run = o, tot = 0;
    #pragma unroll
    for (int sh = 0; sh < 8; sh++) {
        int c = cnt8[(size_t)sh * N + i];
        sbase[(size_t)sh * N + i] = run;
        run += c; tot += c;
    }
    dinv[i] = rsqrtf((float)tot + 1.f);
}

__global__ void k_fill(const int* __restrict__ row, const int* __restrict__ col,
                       const int* __restrict__ sbase, const int* __restrict__ rank,
                       int* __restrict__ csr_rows, int N, int E) {
    int e = blockIdx.x * blockDim.x + threadIdx.x;
    if (e >= E) return;
    int s = (e >> 8) & 7;   // matches k_hist's blockIdx&7 (blockDim=256)
    csr_rows[sbase[(size_t)s * N + col[e]] + rank[e]] = row[e];
}

// ---- maxcut loss over edges ----
__global__ __launch_bounds__(256) void k_loss_edge(const float* __restrict__ probs,
                                                   const int* __restrict__ row,
                                                   const int* __restrict__ col,
                                                   const int* __restrict__ batch,
                                                   float* __restrict__ ed,
                                                   float* __restrict__ ew, int E) {
    __shared__ float bd[GD], be[GD];
    if (threadIdx.x < GD) { bd[threadIdx.x] = 0.f; be[threadIdx.x] = 0.f; }
    __syncthreads();
    for (int e = blockIdx.x * blockDim.x + threadIdx.x; e < E; e += gridDim.x * blockDim.x) {
        int r = row[e];
        float pr = probs[r];
        int b = batch[r];
        atomicAdd(&bd[b], pr);
        atomicAdd(&be[b], pr * probs[col[e]]);
    }
    __syncthreads();
    if (threadIdx.x < GD) {
        atomicAdd(&ed[threadIdx.x], bd[threadIdx.x]);
        atomicAdd(&ew[threadIdx.x], be[threadIdx.x]);
    }
}

__global__ void k_finalize(const float* __restrict__ ed, const float* __restrict__ ew,
                           float* __restrict__ out) {
    int g = threadIdx.x;
    if (g < GD) out[g] = -(ed[g] - ew[g]) * 0.5f;
}

extern "C" void kernel_launch(void* const* d_in, const int* in_sizes, int n_in,
                              void* d_out, int out_size, void* d_ws, size_t ws_size,
                              hipStream_t stream) {
    const float* x     = (const float*)d_in[0];
    const int*   ei    = (const int*)d_in[1];
    const int*   batch = (const int*)d_in[2];
    const float* W_gcn = (const float*)d_in[3];
    const float* b_gcn = (const float*)d_in[4];
    const float* W_gg  = (const float*)d_in[5];
    const float* W_ih  = (const float*)d_in[6];
    const float* W_hh  = (const float*)d_in[7];
    const float* b_ih  = (const float*)d_in[8];
    const float* b_hh  = (const float*)d_in[9];
    const float* W1    = (const float*)d_in[10];
    const float* b1    = (const float*)d_in[11];
    const float* W2    = (const float*)d_in[12];
    const float* b2    = (const float*)d_in[13];
    float* out = (float*)d_out;

    const int N = in_sizes[2];
    const int E = in_sizes[1] / 2;
    const int* row = ei;
    const int* col = ei + E;
    const size_t NH = (size_t)N * HD;

    float* F = (float*)d_ws;
    float* f_h  = F + 0 * NH;
    float* f_xw = F + 1 * NH;
    unsigned short* U = (unsigned short*)(F + 2 * NH);
    unsigned short* x_bf  = U;
    unsigned short* g_bf  = U + 1 * NH;
    unsigned short* t_bf  = U + 2 * NH;
    unsigned short* m_bf  = U + 3 * NH;
    unsigned short* Wq    = U + 4 * NH;
    unsigned short* WgcnT = Wq;               // 16384
    unsigned short* WggT  = Wq + 16384;       // 3*16384
    unsigned short* Wih16 = Wq + 65536;       // 49152
    unsigned short* Whh16 = Wq + 114688;      // 49152
    unsigned short* W1T   = Wq + 163840;      // 16384
    float* S = (float*)(Wq + 180224);
    float* f_dinv  = S;
    float* f_probs = S + N;
    float* f_ed    = S + 2 * N;
    float* f_ew    = f_ed + GD;
    int* I = (int*)(f_ew + GD);
    int* i_cnt8  = I;                   // 8N (zeroed)
    int* i_excl  = I + 8 * N;           // N
    int* i_offs  = I + 9 * N;           // N+1
    int* i_bsum  = I + 10 * N + 8;      // <=64
    int* i_sbase = I + 10 * N + 128;    // 8N
    int* i_rank  = I + 18 * N + 128;    // E
    int* i_csr   = i_rank + E;          // E

    const int nb_scan = (N + SCHUNK - 1) / SCHUNK;
    const int gb32 = (N + 31) / 32;
    const int gb64 = (N + 63) / 64;
    const int gb128 = (N + 127) / 128;
    const int eg = (E + 255) / 256;
    const int ng = (N + 255) / 256;
    const int gather_grid = (N + 3) / 4;

    hipMemsetAsync(i_cnt8, 0, sizeof(int) * 8 * (size_t)N, stream);
    hipMemsetAsync(f_ed, 0, sizeof(float) * 2 * GD, stream);

    // weight prep
    k_prep_w<<<704, 256, 0, stream>>>(W_gcn, W_gg, W_ih, W_hh, W1, Wq);
    k_cast_x<<<(int)((NH / 2 + 255) / 256), 256, 0, stream>>>(x, x_bf, (int)(NH / 2));

    // CSR build
    k_hist<<<eg, 256, 0, stream>>>(col, i_cnt8, i_rank, N, E);
    k_scan1<<<nb_scan, 256, 0, stream>>>(i_cnt8, i_excl, i_bsum, N);
    k_scan2<<<1, 64, 0, stream>>>(i_bsum, nb_scan);
    k_csrfin<<<ng, 256, 0, stream>>>(i_excl, i_bsum, i_cnt8, i_offs, i_sbase, f_dinv, N, E);
    k_fill<<<eg, 256, 0, stream>>>(row, col, i_sbase, i_rank, i_csr, N, E);

    // GCN: xw = x@W_gcn (fp32+bf16); gather+finish -> h fp32, g bf16
    gemm_mfma<<<gb128, 256, 0, stream>>>(x_bf, WgcnT, f_xw, t_bf, N);
    k_gather_gcn<<<gather_grid, 256, 0, stream>>>(t_bf, f_xw, i_csr, i_offs, f_dinv,
                                                  b_gcn, f_h, g_bf, N);

    // GatedGraphConv layers: project -> parallel gather -> 32-row gates+GRU (bf16 state)
    for (int l = 0; l < 3; l++) {
        gemm_mfma<<<gb128, 256, 0, stream>>>(g_bf, WggT + (size_t)l * 16384,
                                             nullptr, t_bf, N);
        k_gather_m<<<gather_grid, 256, 0, stream>>>(t_bf, i_csr, i_offs, m_bf, N);
        k_gru_gates<<<gb32, 256, 0, stream>>>(m_bf, g_bf, Wih16, Whh16, b_ih, b_hh,
                                              g_bf, N);
    }

    // fused head (reads bf16 g state + fp32 h)
    k_head_fused<<<gb64, 256, 0, stream>>>(g_bf, f_h, W1T, b1, W2, b2, f_probs, N);

    // maxcut loss (expected_degree folded into edge pass — exact identity)
    k_loss_edge<<<1024, 256, 0, stream>>>(f_probs, row, col, batch, f_ed, f_ew, E);
    k_finalize<<<1, 64, 0, stream>>>(f_ed, f_ew, out);
}